// Round 9
// baseline (298.113 us; speedup 1.0000x reference)
//
#include <hip/hip_runtime.h>
#include <hip/hip_bf16.h>

#define N_NODES 100000
#define N_EDGES 1600000
#define HID 128
#define N_GRAPHS 256

#define BSHIFT 9
#define BSIZE 512
#define NBUCK ((N_NODES + BSIZE - 1) / BSIZE)   // 196
#define BCAP 10240                               // >> mean 8192 + 22 sigma
#define EPB 8192
#define NBLK_A ((N_EDGES + EPB - 1) / EPB)      // 196

typedef unsigned int uint;
typedef unsigned short ushort;
typedef short short8 __attribute__((ext_vector_type(8)));
typedef float f32x4 __attribute__((ext_vector_type(4)));

__device__ __forceinline__ ushort f2bf_hw(float f) {
    union { __hip_bfloat16 b; ushort u; } cv;
    cv.b = __float2bfloat16(f);
    return cv.u;
}
__device__ __forceinline__ uint4 pack8(const float* r) {
    uint4 o;
    o.x = (uint)f2bf_hw(r[0]) | ((uint)f2bf_hw(r[1]) << 16);
    o.y = (uint)f2bf_hw(r[2]) | ((uint)f2bf_hw(r[3]) << 16);
    o.z = (uint)f2bf_hw(r[4]) | ((uint)f2bf_hw(r[5]) << 16);
    o.w = (uint)f2bf_hw(r[6]) | ((uint)f2bf_hw(r[7]) << 16);
    return o;
}
// accumulate 8 bf16 (packed uint4) into 4 float2 (paired for v_pk_add_f32)
__device__ __forceinline__ void accp(uint4 v, float2* a) {
    a[0].x += __uint_as_float(v.x << 16);
    a[0].y += __uint_as_float(v.x & 0xFFFF0000u);
    a[1].x += __uint_as_float(v.y << 16);
    a[1].y += __uint_as_float(v.y & 0xFFFF0000u);
    a[2].x += __uint_as_float(v.z << 16);
    a[2].y += __uint_as_float(v.z & 0xFFFF0000u);
    a[3].x += __uint_as_float(v.w << 16);
    a[3].y += __uint_as_float(v.w & 0xFFFF0000u);
}

union Frag16 {
    uint4 u;
    short8 s;
    ushort h[8];
};

// ---------------- zero ----------------
__global__ void zero_kernel(int* __restrict__ p, int n) {
    int i = blockIdx.x * blockDim.x + threadIdx.x;
    if (i < n) p[i] = 0;
}

// ---------------- bucketed CSR build (fixed-capacity buckets, single scatter pass) ----------------
__global__ __launch_bounds__(256) void bucket_scatter_kernel(const int* __restrict__ src,
                                                             const int* __restrict__ dst,
                                                             int* __restrict__ bfill,
                                                             uint* __restrict__ bucketed) {
    __shared__ int h[NBUCK];
    __shared__ int rb[NBUCK];
    for (int t = threadIdx.x; t < NBUCK; t += 256) h[t] = 0;
    __syncthreads();
    int base = blockIdx.x * EPB;
#pragma unroll 4
    for (int it = 0; it < EPB / 256; ++it) {
        int e = base + it * 256 + threadIdx.x;
        if (e < N_EDGES) atomicAdd(&h[dst[e] >> BSHIFT], 1);
    }
    __syncthreads();
    for (int t = threadIdx.x; t < NBUCK; t += 256) {
        rb[t] = (h[t] ? atomicAdd(&bfill[t], h[t]) : 0) + t * BCAP;
        h[t] = 0;
    }
    __syncthreads();
#pragma unroll 4
    for (int it = 0; it < EPB / 256; ++it) {
        int e = base + it * 256 + threadIdx.x;
        if (e < N_EDGES) {
            int d = dst[e];
            int b = d >> BSHIFT;
            int pos = rb[b] + atomicAdd(&h[b], 1);
            bucketed[pos] = (uint)src[e] | ((uint)(d & (BSIZE - 1)) << 17);
        }
    }
}

// one block per bucket -> local count/scan/scatter; csr holds BYTE offsets (src*256)
__global__ __launch_bounds__(256) void bucket_csr_kernel(const uint* __restrict__ bucketed,
                                                         const int* __restrict__ bfill,
                                                         int* __restrict__ degi,
                                                         int* __restrict__ rowptr,
                                                         float* __restrict__ dis,
                                                         uint* __restrict__ csrb) {
    int b = blockIdx.x;
    int beg = b * BCAP;
    int ne = bfill[b];
    __shared__ int cnt[BSIZE];
    __shared__ int fl[BSIZE];
    __shared__ int ex[BSIZE];
    __shared__ int ps[256];
    int t = threadIdx.x;
    cnt[t] = 0; cnt[t + 256] = 0;
    fl[t] = 0;  fl[t + 256] = 0;
    __syncthreads();
    for (int i = t; i < ne; i += 256) atomicAdd(&cnt[bucketed[beg + i] >> 17], 1);
    __syncthreads();
    int v0 = cnt[2 * t], v1 = cnt[2 * t + 1];
    int s = v0 + v1;
    ps[t] = s;
    __syncthreads();
    for (int off = 1; off < 256; off <<= 1) {
        int a = (t >= off) ? ps[t - off] : 0;
        __syncthreads();
        ps[t] += a;
        __syncthreads();
    }
    int e0 = ps[t] - s;
    ex[2 * t] = e0;
    ex[2 * t + 1] = e0 + v0;
    int g = b * BSIZE + 2 * t;
    if (g < N_NODES) {
        degi[g] = v0; rowptr[g] = beg + e0;
        dis[g] = rsqrtf(1.0f + (float)v0);
    }
    if (g + 1 < N_NODES) {
        degi[g + 1] = v1; rowptr[g + 1] = beg + e0 + v0;
        dis[g + 1] = rsqrtf(1.0f + (float)v1);
    }
    __syncthreads();
    for (int i = t; i < ne; i += 256) {
        uint u = bucketed[beg + i];
        int dl = u >> 17;
        int p = ex[dl] + atomicAdd(&fl[dl], 1);
        csrb[beg + p] = (u & 0x1FFFFu) << 8;   // byte offset: src * 256
    }
}

// ---------------- W -> B-fragment pre-pack (both layers in one launch) ----------------
__global__ void prep_wfrag2(const float* __restrict__ W1, const float* __restrict__ W2,
                            uint4* __restrict__ WB1, uint4* __restrict__ WB2) {
    int t = blockIdx.x * 256 + threadIdx.x;
    if (t >= 4096) return;
    const float* W = (t < 2048) ? W1 : W2;
    uint4* WB = (t < 2048) ? WB1 : WB2;
    int tt = t & 2047;
    int lane = tt & 63;
    int nt = (tt >> 6) & 7;
    int kt = tt >> 9;
    int kbase = kt * 32 + (lane >> 4) * 8;
    int col = nt * 16 + (lane & 15);
    float r[8];
#pragma unroll
    for (int j = 0; j < 8; j++) r[j] = W[(size_t)(kbase + j) * 128 + col];
    WB[tt] = pack8(r);
}

// ---------------- MFMA GEMM: Y_bf16[M,128] = (X[M,128] @ W) * dis[row] ----------------
// C path staged through LDS for coalesced 16B stores.
template <bool F32IN>
__global__ __launch_bounds__(256) void mgemm_kernel(const void* __restrict__ Xv,
                                                    const uint4* __restrict__ WB,
                                                    const float* __restrict__ dis,
                                                    ushort* __restrict__ Y, int M) {
    __shared__ uint4 WBs[2048];
    __shared__ ushort stage[4][16][136];   // per-wave 16x128 tile, 272B row stride (16B-aligned)
#pragma unroll
    for (int i = 0; i < 8; i++) WBs[i * 256 + threadIdx.x] = WB[i * 256 + threadIdx.x];
    __syncthreads();

    int wave = threadIdx.x >> 6;
    int lane = threadIdx.x & 63;
    int r0 = blockIdx.x * 128 + wave * 32;
    if (r0 >= M) return;  // whole-wave guard; no barriers below

    int rowA = lane & 15;
    int ksub = (lane >> 4) * 8;

    Frag16 a[2][4];
#pragma unroll
    for (int rt = 0; rt < 2; ++rt) {
        int row = r0 + rt * 16 + rowA;
        if (F32IN) {
            const float* xr = (const float*)Xv + (size_t)row * 128;
#pragma unroll
            for (int kt = 0; kt < 4; ++kt) {
                float4 lo = *(const float4*)(xr + kt * 32 + ksub);
                float4 hi = *(const float4*)(xr + kt * 32 + ksub + 4);
                float r[8] = {lo.x, lo.y, lo.z, lo.w, hi.x, hi.y, hi.z, hi.w};
                a[rt][kt].u = pack8(r);
            }
        } else {
            const uint4* xr = (const uint4*)Xv + (size_t)row * 16;
#pragma unroll
            for (int kt = 0; kt < 4; ++kt) a[rt][kt].u = xr[kt * 4 + (lane >> 4)];
        }
    }

    f32x4 acc[2][8];
#pragma unroll
    for (int rt = 0; rt < 2; ++rt)
#pragma unroll
        for (int nt = 0; nt < 8; ++nt) acc[rt][nt] = (f32x4){0.f, 0.f, 0.f, 0.f};

#pragma unroll
    for (int kt = 0; kt < 4; ++kt) {
#pragma unroll
        for (int nt = 0; nt < 8; ++nt) {
            Frag16 b;
            b.u = WBs[(kt * 8 + nt) * 64 + lane];
            acc[0][nt] = __builtin_amdgcn_mfma_f32_16x16x32_bf16(a[0][kt].s, b.s, acc[0][nt], 0, 0, 0);
            acc[1][nt] = __builtin_amdgcn_mfma_f32_16x16x32_bf16(a[1][kt].s, b.s, acc[1][nt], 0, 0, 0);
        }
    }

    // C/D layout: col = lane&15, row = (lane>>4)*4 + reg
    int cbase = lane & 15;
    int rbl = (lane >> 4) * 4;       // local row base 0..12
    ushort* sp = &stage[wave][0][0];
    char* Yb = (char*)Y;
#pragma unroll
    for (int rt = 0; rt < 2; ++rt) {
        int r0g = r0 + rt * 16;
        int rbase = r0g + rbl;
        float d0 = dis[rbase + 0], d1 = dis[rbase + 1];
        float d2 = dis[rbase + 2], d3 = dis[rbase + 3];
#pragma unroll
        for (int nt = 0; nt < 8; ++nt) {
            int col = nt * 16 + cbase;
            sp[(rbl + 0) * 136 + col] = f2bf_hw(acc[rt][nt][0] * d0);
            sp[(rbl + 1) * 136 + col] = f2bf_hw(acc[rt][nt][1] * d1);
            sp[(rbl + 2) * 136 + col] = f2bf_hw(acc[rt][nt][2] * d2);
            sp[(rbl + 3) * 136 + col] = f2bf_hw(acc[rt][nt][3] * d3);
        }
        // per-wave private region: compiler-inserted lgkmcnt orders write->read
#pragma unroll
        for (int i = 0; i < 4; ++i) {
            int idx = i * 64 + lane;
            int row = idx >> 4, c16 = idx & 15;
            uint4 v = *(const uint4*)(sp + row * 136 + c16 * 8);
            *(uint4*)(Yb + (size_t)(r0g + row) * 256 + c16 * 16) = v;
        }
    }
}

// ---------------- aggregation (POOL=1 fuses global-mean-pool dot, skips H write) ----------------
// T holds T' = (X@W)*dis[src] in bf16 rows of 256B. csrb holds BYTE offsets.
// agg[dst] = relu(dis[dst]*(sum T'[nbr] + T'[dst]) + b).
template <int POOL>
__global__ __launch_bounds__(256) void aggregate_kernel(
    const ushort* __restrict__ T, const uint* __restrict__ csrb,
    const int* __restrict__ rowptr, const int* __restrict__ degi,
    const float* __restrict__ dis, const float* __restrict__ bias,
    ushort* __restrict__ H, const int* __restrict__ batch,
    const float* __restrict__ Wfc, float* __restrict__ gsum) {
    __shared__ float pd[4];
    __shared__ int   pg[4];
    int wave = threadIdx.x >> 6;
    int node = blockIdx.x * 4 + wave;     // grid exact: N_NODES % 4 == 0
    int lane = threadIdx.x & 63;
    int group = lane >> 4;
    uint sub16 = (uint)(lane & 15) * 16u;   // byte offset within row

    int start = rowptr[node];
    int cnt = degi[node];
    const char* Tb = (const char*)T;

    float2 acc[4];
#pragma unroll
    for (int i = 0; i < 4; i++) acc[i] = make_float2(0.f, 0.f);

    int j = group;
    for (; j + 12 < cnt; j += 16) {
        uint o0 = csrb[start + j];
        uint o1 = csrb[start + j + 4];
        uint o2 = csrb[start + j + 8];
        uint o3 = csrb[start + j + 12];
        uint4 v0 = *(const uint4*)(Tb + (o0 + sub16));
        uint4 v1 = *(const uint4*)(Tb + (o1 + sub16));
        uint4 v2 = *(const uint4*)(Tb + (o2 + sub16));
        uint4 v3 = *(const uint4*)(Tb + (o3 + sub16));
        accp(v0, acc); accp(v1, acc); accp(v2, acc); accp(v3, acc);
    }
    for (; j < cnt; j += 4) {
        uint o0 = csrb[start + j];
        uint4 v0 = *(const uint4*)(Tb + (o0 + sub16));
        accp(v0, acc);
    }

#pragma unroll
    for (int i = 0; i < 4; i++) {
        acc[i].x += __shfl_xor(acc[i].x, 16);
        acc[i].y += __shfl_xor(acc[i].y, 16);
        acc[i].x += __shfl_xor(acc[i].x, 32);
        acc[i].y += __shfl_xor(acc[i].y, 32);
    }

    if (group == 0) {
        // self term (weight 1), then scale by dis[node], bias, relu
        uint4 sv = *(const uint4*)(Tb + (((uint)node << 8) + sub16));
        accp(sv, acc);
        float di = dis[node];
        int sub = lane & 15;
        float4 blo = ((const float4*)bias)[sub * 2];
        float4 bhi = ((const float4*)bias)[sub * 2 + 1];
        float bb[8] = {blo.x, blo.y, blo.z, blo.w, bhi.x, bhi.y, bhi.z, bhi.w};
        float r[8];
        float af[8] = {acc[0].x, acc[0].y, acc[1].x, acc[1].y,
                       acc[2].x, acc[2].y, acc[3].x, acc[3].y};
#pragma unroll
        for (int i = 0; i < 8; i++) r[i] = fmaxf(di * af[i] + bb[i], 0.f);
        if (POOL == 0) {
            ((uint4*)H)[(size_t)node * 16 + sub] = pack8(r);
        } else {
            float4 wlo = ((const float4*)Wfc)[sub * 2];
            float4 whi = ((const float4*)Wfc)[sub * 2 + 1];
            float d = r[0] * wlo.x + r[1] * wlo.y + r[2] * wlo.z + r[3] * wlo.w
                    + r[4] * whi.x + r[5] * whi.y + r[6] * whi.z + r[7] * whi.w;
            d += __shfl_xor(d, 1);
            d += __shfl_xor(d, 2);
            d += __shfl_xor(d, 4);
            d += __shfl_xor(d, 8);
            if (sub == 0) { pd[wave] = d; pg[wave] = batch[node]; }
        }
    }
    if (POOL == 1) {
        __syncthreads();
        if (threadIdx.x == 0) {
            // sorted batch: combine same-graph runs within the block (usually 1 atomic)
            float s = pd[0]; int g = pg[0];
#pragma unroll
            for (int w = 1; w < 4; ++w) {
                if (pg[w] == g) s += pd[w];
                else { atomicAdd(&gsum[g], s); g = pg[w]; s = pd[w]; }
            }
            atomicAdd(&gsum[g], s);
        }
    }
}

// ---------------- finalize: counts via binary search on sorted batch ----------------
__global__ void finalize_kernel(const float* __restrict__ gsum, const int* __restrict__ batch,
                                const float* __restrict__ bfc, float* __restrict__ out) {
    int g = threadIdx.x;
    if (g >= N_GRAPHS) return;
    auto lb = [&](int key) {
        int lo = 0, hi = N_NODES;
        while (lo < hi) {
            int mid = (lo + hi) >> 1;
            if (batch[mid] < key) lo = mid + 1; else hi = mid;
        }
        return lo;
    };
    int a = lb(g), b = lb(g + 1);
    float cnt = (float)(b - a);
    out[g] = gsum[g] / fmaxf(cnt, 1.0f) + bfc[0];
}

// ---------------- launcher ----------------
extern "C" void kernel_launch(void* const* d_in, const int* in_sizes, int n_in,
                              void* d_out, int out_size, void* d_ws, size_t ws_size,
                              hipStream_t stream) {
    const float* x    = (const float*)d_in[0];
    const int*   eidx = (const int*)d_in[1];
    const int*   batch= (const int*)d_in[2];
    const float* W1   = (const float*)d_in[3];
    const float* b1   = (const float*)d_in[4];
    const float* W2   = (const float*)d_in[5];
    const float* b2   = (const float*)d_in[6];
    const float* Wfc  = (const float*)d_in[7];
    const float* bfc  = (const float*)d_in[8];
    float* out = (float*)d_out;

    const int* src = eidx;
    const int* dst = eidx + N_EDGES;

    size_t off = 0;
    char* base = (char*)d_ws;
    auto alloc = [&](size_t bytes) -> void* {
        void* p = base + off;
        off += (bytes + 255) & ~(size_t)255;
        return p;
    };
    // zeroed region first: bfill, gsum
    int*    bfill  = (int*)alloc(NBUCK * 4);
    float*  gsum   = (float*)alloc(N_GRAPHS * 4);
    size_t zero_bytes = off;
    ushort* A      = (ushort*)alloc((size_t)N_NODES * HID * 2);
    ushort* B      = (ushort*)alloc((size_t)N_NODES * HID * 2);
    int*    degi   = (int*)alloc(N_NODES * 4);
    int*    rowptr = (int*)alloc(N_NODES * 4);
    float*  dis    = (float*)alloc(N_NODES * 4);
    uint*   csrb   = (uint*)alloc((size_t)NBUCK * BCAP * 4);
    uint*   bucketed = (uint*)alloc((size_t)NBUCK * BCAP * 4);
    uint4*  WB1    = (uint4*)alloc(2048 * 16);
    uint4*  WB2    = (uint4*)alloc(2048 * 16);

    int zn = (int)(zero_bytes / 4);
    zero_kernel<<<(zn + 255) / 256, 256, 0, stream>>>((int*)base, zn);

    // bucketed CSR build (fixed-capacity, 2 passes total)
    bucket_scatter_kernel<<<NBLK_A, 256, 0, stream>>>(src, dst, bfill, bucketed);
    bucket_csr_kernel<<<NBUCK, 256, 0, stream>>>(bucketed, bfill, degi, rowptr, dis, csrb);

    // W fragment pre-pack (both layers)
    prep_wfrag2<<<16, 256, 0, stream>>>(W1, W2, WB1, WB2);

    int gemm_grid = (N_NODES + 127) / 128;
    int agg_grid  = N_NODES / 4;   // exact

    // layer 1
    mgemm_kernel<true><<<gemm_grid, 256, 0, stream>>>(x, WB1, dis, A, N_NODES);
    aggregate_kernel<0><<<agg_grid, 256, 0, stream>>>(A, csrb, rowptr, degi, dis, b1, B,
                                                      batch, Wfc, gsum);
    // layer 2
    mgemm_kernel<false><<<gemm_grid, 256, 0, stream>>>(B, WB2, dis, A, N_NODES);
    aggregate_kernel<1><<<agg_grid, 256, 0, stream>>>(A, csrb, rowptr, degi, dis, b2, B,
                                                      batch, Wfc, gsum);

    // fc
    finalize_kernel<<<1, 256, 0, stream>>>(gsum, batch, bfc, out);
}

// Round 10
// 228.363 us; speedup vs baseline: 1.3054x; 1.3054x over previous
//
#include <hip/hip_runtime.h>
#include <hip/hip_bf16.h>

#define N_NODES 100000
#define N_EDGES 1600000
#define HID 128
#define N_GRAPHS 256

#define BSHIFT 9
#define BSIZE 512
#define NBUCK ((N_NODES + BSIZE - 1) / BSIZE)   // 196
#define BCAP 10240                               // >> mean 8192 + 22 sigma
#define EPB 8192
#define NBLK_A ((N_EDGES + EPB - 1) / EPB)      // 196

typedef unsigned int uint;
typedef unsigned short ushort;
typedef short short8 __attribute__((ext_vector_type(8)));
typedef float f32x4 __attribute__((ext_vector_type(4)));

__device__ __forceinline__ ushort f2bf_hw(float f) {
    union { __hip_bfloat16 b; ushort u; } cv;
    cv.b = __float2bfloat16(f);
    return cv.u;
}
__device__ __forceinline__ uint4 pack8(const float* r) {
    uint4 o;
    o.x = (uint)f2bf_hw(r[0]) | ((uint)f2bf_hw(r[1]) << 16);
    o.y = (uint)f2bf_hw(r[2]) | ((uint)f2bf_hw(r[3]) << 16);
    o.z = (uint)f2bf_hw(r[4]) | ((uint)f2bf_hw(r[5]) << 16);
    o.w = (uint)f2bf_hw(r[6]) | ((uint)f2bf_hw(r[7]) << 16);
    return o;
}
// accumulate 8 bf16 (packed uint4) into 4 float2 (paired for v_pk_add_f32)
__device__ __forceinline__ void accp(uint4 v, float2* a) {
    a[0].x += __uint_as_float(v.x << 16);
    a[0].y += __uint_as_float(v.x & 0xFFFF0000u);
    a[1].x += __uint_as_float(v.y << 16);
    a[1].y += __uint_as_float(v.y & 0xFFFF0000u);
    a[2].x += __uint_as_float(v.z << 16);
    a[2].y += __uint_as_float(v.z & 0xFFFF0000u);
    a[3].x += __uint_as_float(v.w << 16);
    a[3].y += __uint_as_float(v.w & 0xFFFF0000u);
}

union Frag16 {
    uint4 u;
    short8 s;
    ushort h[8];
};

// ---------------- zero ----------------
__global__ void zero_kernel(int* __restrict__ p, int n) {
    int i = blockIdx.x * blockDim.x + threadIdx.x;
    if (i < n) p[i] = 0;
}

// ---------------- bucketed CSR build (fixed-capacity buckets, single scatter pass) ----------------
__global__ __launch_bounds__(256) void bucket_scatter_kernel(const int* __restrict__ src,
                                                             const int* __restrict__ dst,
                                                             int* __restrict__ bfill,
                                                             uint* __restrict__ bucketed) {
    __shared__ int h[NBUCK];
    __shared__ int rb[NBUCK];
    for (int t = threadIdx.x; t < NBUCK; t += 256) h[t] = 0;
    __syncthreads();
    int base = blockIdx.x * EPB;
#pragma unroll 4
    for (int it = 0; it < EPB / 256; ++it) {
        int e = base + it * 256 + threadIdx.x;
        if (e < N_EDGES) atomicAdd(&h[dst[e] >> BSHIFT], 1);
    }
    __syncthreads();
    for (int t = threadIdx.x; t < NBUCK; t += 256) {
        rb[t] = (h[t] ? atomicAdd(&bfill[t], h[t]) : 0) + t * BCAP;
        h[t] = 0;
    }
    __syncthreads();
#pragma unroll 4
    for (int it = 0; it < EPB / 256; ++it) {
        int e = base + it * 256 + threadIdx.x;
        if (e < N_EDGES) {
            int d = dst[e];
            int b = d >> BSHIFT;
            int pos = rb[b] + atomicAdd(&h[b], 1);
            bucketed[pos] = (uint)src[e] | ((uint)(d & (BSIZE - 1)) << 17);
        }
    }
}

// one block per bucket -> local count/scan/scatter; csr holds BYTE offsets (src*256)
__global__ __launch_bounds__(256) void bucket_csr_kernel(const uint* __restrict__ bucketed,
                                                         const int* __restrict__ bfill,
                                                         int* __restrict__ degi,
                                                         int* __restrict__ rowptr,
                                                         float* __restrict__ dis,
                                                         uint* __restrict__ csrb) {
    int b = blockIdx.x;
    int beg = b * BCAP;
    int ne = bfill[b];
    __shared__ int cnt[BSIZE];
    __shared__ int fl[BSIZE];
    __shared__ int ex[BSIZE];
    __shared__ int ps[256];
    int t = threadIdx.x;
    cnt[t] = 0; cnt[t + 256] = 0;
    fl[t] = 0;  fl[t + 256] = 0;
    __syncthreads();
    for (int i = t; i < ne; i += 256) atomicAdd(&cnt[bucketed[beg + i] >> 17], 1);
    __syncthreads();
    int v0 = cnt[2 * t], v1 = cnt[2 * t + 1];
    int s = v0 + v1;
    ps[t] = s;
    __syncthreads();
    for (int off = 1; off < 256; off <<= 1) {
        int a = (t >= off) ? ps[t - off] : 0;
        __syncthreads();
        ps[t] += a;
        __syncthreads();
    }
    int e0 = ps[t] - s;
    ex[2 * t] = e0;
    ex[2 * t + 1] = e0 + v0;
    int g = b * BSIZE + 2 * t;
    if (g < N_NODES) {
        degi[g] = v0; rowptr[g] = beg + e0;
        dis[g] = rsqrtf(1.0f + (float)v0);
    }
    if (g + 1 < N_NODES) {
        degi[g + 1] = v1; rowptr[g + 1] = beg + e0 + v0;
        dis[g + 1] = rsqrtf(1.0f + (float)v1);
    }
    __syncthreads();
    for (int i = t; i < ne; i += 256) {
        uint u = bucketed[beg + i];
        int dl = u >> 17;
        int p = ex[dl] + atomicAdd(&fl[dl], 1);
        csrb[beg + p] = (u & 0x1FFFFu) << 8;   // byte offset: src * 256
    }
}

// ---------------- W -> B-fragment pre-pack (both layers in one launch) ----------------
__global__ void prep_wfrag2(const float* __restrict__ W1, const float* __restrict__ W2,
                            uint4* __restrict__ WB1, uint4* __restrict__ WB2) {
    int t = blockIdx.x * 256 + threadIdx.x;
    if (t >= 4096) return;
    const float* W = (t < 2048) ? W1 : W2;
    uint4* WB = (t < 2048) ? WB1 : WB2;
    int tt = t & 2047;
    int lane = tt & 63;
    int nt = (tt >> 6) & 7;
    int kt = tt >> 9;
    int kbase = kt * 32 + (lane >> 4) * 8;
    int col = nt * 16 + (lane & 15);
    float r[8];
#pragma unroll
    for (int j = 0; j < 8; j++) r[j] = W[(size_t)(kbase + j) * 128 + col];
    WB[tt] = pack8(r);
}

// ---------------- MFMA GEMM: Y_bf16[M,128] = (X[M,128] @ W) * dis[row] ----------------
// C path staged through LDS for coalesced 16B stores.
template <bool F32IN>
__global__ __launch_bounds__(256) void mgemm_kernel(const void* __restrict__ Xv,
                                                    const uint4* __restrict__ WB,
                                                    const float* __restrict__ dis,
                                                    ushort* __restrict__ Y, int M) {
    __shared__ uint4 WBs[2048];
    __shared__ ushort stage[4][16][136];   // per-wave 16x128 tile, 272B row stride
#pragma unroll
    for (int i = 0; i < 8; i++) WBs[i * 256 + threadIdx.x] = WB[i * 256 + threadIdx.x];
    __syncthreads();

    int wave = threadIdx.x >> 6;
    int lane = threadIdx.x & 63;
    int r0 = blockIdx.x * 128 + wave * 32;
    if (r0 >= M) return;  // whole-wave guard; no barriers below

    int rowA = lane & 15;
    int ksub = (lane >> 4) * 8;

    Frag16 a[2][4];
#pragma unroll
    for (int rt = 0; rt < 2; ++rt) {
        int row = r0 + rt * 16 + rowA;
        if (F32IN) {
            const float* xr = (const float*)Xv + (size_t)row * 128;
#pragma unroll
            for (int kt = 0; kt < 4; ++kt) {
                float4 lo = *(const float4*)(xr + kt * 32 + ksub);
                float4 hi = *(const float4*)(xr + kt * 32 + ksub + 4);
                float r[8] = {lo.x, lo.y, lo.z, lo.w, hi.x, hi.y, hi.z, hi.w};
                a[rt][kt].u = pack8(r);
            }
        } else {
            const uint4* xr = (const uint4*)Xv + (size_t)row * 16;
#pragma unroll
            for (int kt = 0; kt < 4; ++kt) a[rt][kt].u = xr[kt * 4 + (lane >> 4)];
        }
    }

    f32x4 acc[2][8];
#pragma unroll
    for (int rt = 0; rt < 2; ++rt)
#pragma unroll
        for (int nt = 0; nt < 8; ++nt) acc[rt][nt] = (f32x4){0.f, 0.f, 0.f, 0.f};

#pragma unroll
    for (int kt = 0; kt < 4; ++kt) {
#pragma unroll
        for (int nt = 0; nt < 8; ++nt) {
            Frag16 b;
            b.u = WBs[(kt * 8 + nt) * 64 + lane];
            acc[0][nt] = __builtin_amdgcn_mfma_f32_16x16x32_bf16(a[0][kt].s, b.s, acc[0][nt], 0, 0, 0);
            acc[1][nt] = __builtin_amdgcn_mfma_f32_16x16x32_bf16(a[1][kt].s, b.s, acc[1][nt], 0, 0, 0);
        }
    }

    // C/D layout: col = lane&15, row = (lane>>4)*4 + reg
    int cbase = lane & 15;
    int rbl = (lane >> 4) * 4;
    ushort* sp = &stage[wave][0][0];
    char* Yb = (char*)Y;
#pragma unroll
    for (int rt = 0; rt < 2; ++rt) {
        int r0g = r0 + rt * 16;
        int rbase = r0g + rbl;
        float d0 = dis[rbase + 0], d1 = dis[rbase + 1];
        float d2 = dis[rbase + 2], d3 = dis[rbase + 3];
#pragma unroll
        for (int nt = 0; nt < 8; ++nt) {
            int col = nt * 16 + cbase;
            sp[(rbl + 0) * 136 + col] = f2bf_hw(acc[rt][nt][0] * d0);
            sp[(rbl + 1) * 136 + col] = f2bf_hw(acc[rt][nt][1] * d1);
            sp[(rbl + 2) * 136 + col] = f2bf_hw(acc[rt][nt][2] * d2);
            sp[(rbl + 3) * 136 + col] = f2bf_hw(acc[rt][nt][3] * d3);
        }
#pragma unroll
        for (int i = 0; i < 4; ++i) {
            int idx = i * 64 + lane;
            int row = idx >> 4, c16 = idx & 15;
            uint4 v = *(const uint4*)(sp + row * 136 + c16 * 8);
            *(uint4*)(Yb + (size_t)(r0g + row) * 256 + c16 * 16) = v;
        }
    }
}

// ---------------- aggregation (POOL=1: write per-node FC dot, no H write, no atomics) ----------------
// T holds T' = (X@W)*dis[src] in bf16 rows of 256B. csrb holds BYTE offsets.
// agg[dst] = relu(dis[dst]*(sum T'[nbr] + T'[dst]) + b).
template <int POOL>
__global__ __launch_bounds__(256) void aggregate_kernel(
    const ushort* __restrict__ T, const uint* __restrict__ csrb,
    const int* __restrict__ rowptr, const int* __restrict__ degi,
    const float* __restrict__ dis, const float* __restrict__ bias,
    ushort* __restrict__ H, const float* __restrict__ Wfc,
    float* __restrict__ ndot) {
    int wave = threadIdx.x >> 6;
    int node = blockIdx.x * 4 + wave;     // grid exact: N_NODES % 4 == 0
    int lane = threadIdx.x & 63;
    int group = lane >> 4;
    uint sub16 = (uint)(lane & 15) * 16u;

    int start = rowptr[node];
    int cnt = degi[node];
    const char* Tb = (const char*)T;

    float2 acc[4];
#pragma unroll
    for (int i = 0; i < 4; i++) acc[i] = make_float2(0.f, 0.f);

    int j = group;
    for (; j + 12 < cnt; j += 16) {
        uint o0 = csrb[start + j];
        uint o1 = csrb[start + j + 4];
        uint o2 = csrb[start + j + 8];
        uint o3 = csrb[start + j + 12];
        uint4 v0 = *(const uint4*)(Tb + (o0 + sub16));
        uint4 v1 = *(const uint4*)(Tb + (o1 + sub16));
        uint4 v2 = *(const uint4*)(Tb + (o2 + sub16));
        uint4 v3 = *(const uint4*)(Tb + (o3 + sub16));
        accp(v0, acc); accp(v1, acc); accp(v2, acc); accp(v3, acc);
    }
    for (; j < cnt; j += 4) {
        uint o0 = csrb[start + j];
        uint4 v0 = *(const uint4*)(Tb + (o0 + sub16));
        accp(v0, acc);
    }

#pragma unroll
    for (int i = 0; i < 4; i++) {
        acc[i].x += __shfl_xor(acc[i].x, 16);
        acc[i].y += __shfl_xor(acc[i].y, 16);
        acc[i].x += __shfl_xor(acc[i].x, 32);
        acc[i].y += __shfl_xor(acc[i].y, 32);
    }

    if (group == 0) {
        // self term (weight 1), then scale by dis[node], bias, relu
        uint4 sv = *(const uint4*)(Tb + (((uint)node << 8) + sub16));
        accp(sv, acc);
        float di = dis[node];
        int sub = lane & 15;
        float4 blo = ((const float4*)bias)[sub * 2];
        float4 bhi = ((const float4*)bias)[sub * 2 + 1];
        float bb[8] = {blo.x, blo.y, blo.z, blo.w, bhi.x, bhi.y, bhi.z, bhi.w};
        float r[8];
        float af[8] = {acc[0].x, acc[0].y, acc[1].x, acc[1].y,
                       acc[2].x, acc[2].y, acc[3].x, acc[3].y};
#pragma unroll
        for (int i = 0; i < 8; i++) r[i] = fmaxf(di * af[i] + bb[i], 0.f);
        if (POOL == 0) {
            ((uint4*)H)[(size_t)node * 16 + sub] = pack8(r);
        } else {
            float4 wlo = ((const float4*)Wfc)[sub * 2];
            float4 whi = ((const float4*)Wfc)[sub * 2 + 1];
            float d = r[0] * wlo.x + r[1] * wlo.y + r[2] * wlo.z + r[3] * wlo.w
                    + r[4] * whi.x + r[5] * whi.y + r[6] * whi.z + r[7] * whi.w;
            d += __shfl_xor(d, 1);
            d += __shfl_xor(d, 2);
            d += __shfl_xor(d, 4);
            d += __shfl_xor(d, 8);
            if (sub == 0) ndot[node] = d;   // plain store, no atomic, no barrier
        }
    }
}

// ---------------- pool+fc: one wave per graph over sorted batch ----------------
__global__ __launch_bounds__(64) void pool_fc_kernel(const float* __restrict__ ndot,
                                                     const int* __restrict__ batch,
                                                     const float* __restrict__ bfc,
                                                     float* __restrict__ out) {
    int g = blockIdx.x;
    int lane = threadIdx.x;
    auto lb = [&](int key) {
        int lo = 0, hi = N_NODES;
        while (lo < hi) {
            int mid = (lo + hi) >> 1;
            if (batch[mid] < key) lo = mid + 1; else hi = mid;
        }
        return lo;
    };
    int a = lb(g), b = lb(g + 1);
    float s = 0.f;
    for (int i = a + lane; i < b; i += 64) s += ndot[i];
#pragma unroll
    for (int off = 32; off > 0; off >>= 1) s += __shfl_down(s, off);
    if (lane == 0) out[g] = s / fmaxf((float)(b - a), 1.0f) + bfc[0];
}

// ---------------- launcher ----------------
extern "C" void kernel_launch(void* const* d_in, const int* in_sizes, int n_in,
                              void* d_out, int out_size, void* d_ws, size_t ws_size,
                              hipStream_t stream) {
    const float* x    = (const float*)d_in[0];
    const int*   eidx = (const int*)d_in[1];
    const int*   batch= (const int*)d_in[2];
    const float* W1   = (const float*)d_in[3];
    const float* b1   = (const float*)d_in[4];
    const float* W2   = (const float*)d_in[5];
    const float* b2   = (const float*)d_in[6];
    const float* Wfc  = (const float*)d_in[7];
    const float* bfc  = (const float*)d_in[8];
    float* out = (float*)d_out;

    const int* src = eidx;
    const int* dst = eidx + N_EDGES;

    size_t off = 0;
    char* base = (char*)d_ws;
    auto alloc = [&](size_t bytes) -> void* {
        void* p = base + off;
        off += (bytes + 255) & ~(size_t)255;
        return p;
    };
    // zeroed region first: bfill
    int*    bfill  = (int*)alloc(NBUCK * 4);
    size_t zero_bytes = off;
    ushort* A      = (ushort*)alloc((size_t)N_NODES * HID * 2);
    ushort* B      = (ushort*)alloc((size_t)N_NODES * HID * 2);
    int*    degi   = (int*)alloc(N_NODES * 4);
    int*    rowptr = (int*)alloc(N_NODES * 4);
    float*  dis    = (float*)alloc(N_NODES * 4);
    float*  ndot   = (float*)alloc(N_NODES * 4);
    uint*   csrb   = (uint*)alloc((size_t)NBUCK * BCAP * 4);
    uint*   bucketed = (uint*)alloc((size_t)NBUCK * BCAP * 4);
    uint4*  WB1    = (uint4*)alloc(2048 * 16);
    uint4*  WB2    = (uint4*)alloc(2048 * 16);

    int zn = (int)(zero_bytes / 4);
    zero_kernel<<<1, 256, 0, stream>>>((int*)base, zn);

    // bucketed CSR build (fixed-capacity, 2 passes total)
    bucket_scatter_kernel<<<NBLK_A, 256, 0, stream>>>(src, dst, bfill, bucketed);
    bucket_csr_kernel<<<NBUCK, 256, 0, stream>>>(bucketed, bfill, degi, rowptr, dis, csrb);

    // W fragment pre-pack (both layers)
    prep_wfrag2<<<16, 256, 0, stream>>>(W1, W2, WB1, WB2);

    int gemm_grid = (N_NODES + 127) / 128;
    int agg_grid  = N_NODES / 4;   // exact

    // layer 1
    mgemm_kernel<true><<<gemm_grid, 256, 0, stream>>>(x, WB1, dis, A, N_NODES);
    aggregate_kernel<0><<<agg_grid, 256, 0, stream>>>(A, csrb, rowptr, degi, dis, b1, B,
                                                      Wfc, ndot);
    // layer 2
    mgemm_kernel<false><<<gemm_grid, 256, 0, stream>>>(B, WB2, dis, A, N_NODES);
    aggregate_kernel<1><<<agg_grid, 256, 0, stream>>>(A, csrb, rowptr, degi, dis, b2, B,
                                                      Wfc, ndot);

    // pool + fc
    pool_fc_kernel<<<N_GRAPHS, 64, 0, stream>>>(ndot, batch, bfc, out);
}

// Round 11
// 227.535 us; speedup vs baseline: 1.3102x; 1.0036x over previous
//
#include <hip/hip_runtime.h>
#include <hip/hip_bf16.h>

#define N_NODES 100000
#define N_EDGES 1600000
#define HID 128
#define N_GRAPHS 256

#define BSHIFT 9
#define BSIZE 512
#define NBUCK ((N_NODES + BSIZE - 1) / BSIZE)   // 196
#define BCAP 14336                               // padded worst case: ~8800 + 512*15/2
#define EPB 8192
#define NBLK_A ((N_EDGES + EPB - 1) / EPB)      // 196
#define ZOFF ((uint)N_NODES << 8)                // byte offset of the zero row

typedef unsigned int uint;
typedef unsigned short ushort;
typedef short short8 __attribute__((ext_vector_type(8)));
typedef float f32x4 __attribute__((ext_vector_type(4)));

__device__ __forceinline__ ushort f2bf_hw(float f) {
    union { __hip_bfloat16 b; ushort u; } cv;
    cv.b = __float2bfloat16(f);
    return cv.u;
}
__device__ __forceinline__ uint4 pack8(const float* r) {
    uint4 o;
    o.x = (uint)f2bf_hw(r[0]) | ((uint)f2bf_hw(r[1]) << 16);
    o.y = (uint)f2bf_hw(r[2]) | ((uint)f2bf_hw(r[3]) << 16);
    o.z = (uint)f2bf_hw(r[4]) | ((uint)f2bf_hw(r[5]) << 16);
    o.w = (uint)f2bf_hw(r[6]) | ((uint)f2bf_hw(r[7]) << 16);
    return o;
}
// accumulate 8 bf16 (packed uint4) into 4 float2 (paired for v_pk_add_f32)
__device__ __forceinline__ void accp(uint4 v, float2* a) {
    a[0].x += __uint_as_float(v.x << 16);
    a[0].y += __uint_as_float(v.x & 0xFFFF0000u);
    a[1].x += __uint_as_float(v.y << 16);
    a[1].y += __uint_as_float(v.y & 0xFFFF0000u);
    a[2].x += __uint_as_float(v.z << 16);
    a[2].y += __uint_as_float(v.z & 0xFFFF0000u);
    a[3].x += __uint_as_float(v.w << 16);
    a[3].y += __uint_as_float(v.w & 0xFFFF0000u);
}

union Frag16 {
    uint4 u;
    short8 s;
    ushort h[8];
};

// ---------------- init: zero bfill + the dummy zero rows of A and B ----------------
__global__ void init_kernel(int* __restrict__ bfill, uint4* __restrict__ Azr,
                            uint4* __restrict__ Bzr) {
    int t = threadIdx.x;
    if (t < NBUCK) bfill[t] = 0;
    if (t < 16) Azr[t] = (uint4){0, 0, 0, 0};
    else if (t < 32) Bzr[t - 16] = (uint4){0, 0, 0, 0};
}

// ---------------- bucketed CSR build (fixed-capacity buckets, single scatter pass) ----------------
__global__ __launch_bounds__(256) void bucket_scatter_kernel(const int* __restrict__ src,
                                                             const int* __restrict__ dst,
                                                             int* __restrict__ bfill,
                                                             uint* __restrict__ bucketed) {
    __shared__ int h[NBUCK];
    __shared__ int rb[NBUCK];
    for (int t = threadIdx.x; t < NBUCK; t += 256) h[t] = 0;
    __syncthreads();
    int base = blockIdx.x * EPB;
#pragma unroll 4
    for (int it = 0; it < EPB / 256; ++it) {
        int e = base + it * 256 + threadIdx.x;
        if (e < N_EDGES) atomicAdd(&h[dst[e] >> BSHIFT], 1);
    }
    __syncthreads();
    for (int t = threadIdx.x; t < NBUCK; t += 256) {
        rb[t] = (h[t] ? atomicAdd(&bfill[t], h[t]) : 0) + t * BCAP;
        h[t] = 0;
    }
    __syncthreads();
#pragma unroll 4
    for (int it = 0; it < EPB / 256; ++it) {
        int e = base + it * 256 + threadIdx.x;
        if (e < N_EDGES) {
            int d = dst[e];
            int b = d >> BSHIFT;
            int pos = rb[b] + atomicAdd(&h[b], 1);
            bucketed[pos] = (uint)src[e] | ((uint)(d & (BSIZE - 1)) << 17);
        }
    }
}

// one block per bucket -> local count/scan/scatter.
// Segments PADDED to multiples of 16 with ZOFF; degi holds the PADDED count.
__global__ __launch_bounds__(256) void bucket_csr_kernel(const uint* __restrict__ bucketed,
                                                         const int* __restrict__ bfill,
                                                         int* __restrict__ degi,
                                                         int* __restrict__ rowptr,
                                                         float* __restrict__ dis,
                                                         uint* __restrict__ csrb) {
    int b = blockIdx.x;
    int beg = b * BCAP;
    int ne = bfill[b];
    __shared__ int cnt[BSIZE];
    __shared__ int fl[BSIZE];
    __shared__ int ex[BSIZE];
    __shared__ int ps[256];
    int t = threadIdx.x;
    cnt[t] = 0; cnt[t + 256] = 0;
    fl[t] = 0;  fl[t + 256] = 0;
    __syncthreads();
    for (int i = t; i < ne; i += 256) atomicAdd(&cnt[bucketed[beg + i] >> 17], 1);
    __syncthreads();
    int v0 = cnt[2 * t], v1 = cnt[2 * t + 1];
    int p0 = (v0 + 15) & ~15;           // padded sizes
    int p1 = (v1 + 15) & ~15;
    int s = p0 + p1;
    ps[t] = s;
    __syncthreads();
    for (int off = 1; off < 256; off <<= 1) {
        int a = (t >= off) ? ps[t - off] : 0;
        __syncthreads();
        ps[t] += a;
        __syncthreads();
    }
    int e0 = ps[t] - s;
    ex[2 * t] = e0;
    ex[2 * t + 1] = e0 + p0;
    int g = b * BSIZE + 2 * t;
    if (g < N_NODES) {
        degi[g] = p0; rowptr[g] = beg + e0;
        dis[g] = rsqrtf(1.0f + (float)v0);
    }
    if (g + 1 < N_NODES) {
        degi[g + 1] = p1; rowptr[g + 1] = beg + e0 + p0;
        dis[g + 1] = rsqrtf(1.0f + (float)v1);
    }
    __syncthreads();
    for (int i = t; i < ne; i += 256) {
        uint u = bucketed[beg + i];
        int dl = u >> 17;
        int p = ex[dl] + atomicAdd(&fl[dl], 1);
        csrb[beg + p] = (u & 0x1FFFFu) << 8;   // byte offset: src * 256
    }
    __syncthreads();
    // fill pad slots with the zero-row offset
    for (int p = v0; p < p0; ++p) csrb[beg + ex[2 * t] + p] = ZOFF;
    for (int p = v1; p < p1; ++p) csrb[beg + ex[2 * t + 1] + p] = ZOFF;
}

// ---------------- W -> B-fragment pre-pack (both layers in one launch) ----------------
__global__ void prep_wfrag2(const float* __restrict__ W1, const float* __restrict__ W2,
                            uint4* __restrict__ WB1, uint4* __restrict__ WB2) {
    int t = blockIdx.x * 256 + threadIdx.x;
    if (t >= 4096) return;
    const float* W = (t < 2048) ? W1 : W2;
    uint4* WB = (t < 2048) ? WB1 : WB2;
    int tt = t & 2047;
    int lane = tt & 63;
    int nt = (tt >> 6) & 7;
    int kt = tt >> 9;
    int kbase = kt * 32 + (lane >> 4) * 8;
    int col = nt * 16 + (lane & 15);
    float r[8];
#pragma unroll
    for (int j = 0; j < 8; j++) r[j] = W[(size_t)(kbase + j) * 128 + col];
    WB[tt] = pack8(r);
}

// ---------------- MFMA GEMM: Y_bf16[M,128] = (X[M,128] @ W) * dis[row] ----------------
// C path staged through LDS for coalesced 16B stores.
template <bool F32IN>
__global__ __launch_bounds__(256) void mgemm_kernel(const void* __restrict__ Xv,
                                                    const uint4* __restrict__ WB,
                                                    const float* __restrict__ dis,
                                                    ushort* __restrict__ Y, int M) {
    __shared__ uint4 WBs[2048];
    __shared__ ushort stage[4][16][136];   // per-wave 16x128 tile, 272B row stride
#pragma unroll
    for (int i = 0; i < 8; i++) WBs[i * 256 + threadIdx.x] = WB[i * 256 + threadIdx.x];
    __syncthreads();

    int wave = threadIdx.x >> 6;
    int lane = threadIdx.x & 63;
    int r0 = blockIdx.x * 128 + wave * 32;
    if (r0 >= M) return;  // whole-wave guard; no barriers below

    int rowA = lane & 15;
    int ksub = (lane >> 4) * 8;

    Frag16 a[2][4];
#pragma unroll
    for (int rt = 0; rt < 2; ++rt) {
        int row = r0 + rt * 16 + rowA;
        if (F32IN) {
            const float* xr = (const float*)Xv + (size_t)row * 128;
#pragma unroll
            for (int kt = 0; kt < 4; ++kt) {
                float4 lo = *(const float4*)(xr + kt * 32 + ksub);
                float4 hi = *(const float4*)(xr + kt * 32 + ksub + 4);
                float r[8] = {lo.x, lo.y, lo.z, lo.w, hi.x, hi.y, hi.z, hi.w};
                a[rt][kt].u = pack8(r);
            }
        } else {
            const uint4* xr = (const uint4*)Xv + (size_t)row * 16;
#pragma unroll
            for (int kt = 0; kt < 4; ++kt) a[rt][kt].u = xr[kt * 4 + (lane >> 4)];
        }
    }

    f32x4 acc[2][8];
#pragma unroll
    for (int rt = 0; rt < 2; ++rt)
#pragma unroll
        for (int nt = 0; nt < 8; ++nt) acc[rt][nt] = (f32x4){0.f, 0.f, 0.f, 0.f};

#pragma unroll
    for (int kt = 0; kt < 4; ++kt) {
#pragma unroll
        for (int nt = 0; nt < 8; ++nt) {
            Frag16 b;
            b.u = WBs[(kt * 8 + nt) * 64 + lane];
            acc[0][nt] = __builtin_amdgcn_mfma_f32_16x16x32_bf16(a[0][kt].s, b.s, acc[0][nt], 0, 0, 0);
            acc[1][nt] = __builtin_amdgcn_mfma_f32_16x16x32_bf16(a[1][kt].s, b.s, acc[1][nt], 0, 0, 0);
        }
    }

    // C/D layout: col = lane&15, row = (lane>>4)*4 + reg
    int cbase = lane & 15;
    int rbl = (lane >> 4) * 4;
    ushort* sp = &stage[wave][0][0];
    char* Yb = (char*)Y;
#pragma unroll
    for (int rt = 0; rt < 2; ++rt) {
        int r0g = r0 + rt * 16;
        int rbase = r0g + rbl;
        float d0 = dis[rbase + 0], d1 = dis[rbase + 1];
        float d2 = dis[rbase + 2], d3 = dis[rbase + 3];
#pragma unroll
        for (int nt = 0; nt < 8; ++nt) {
            int col = nt * 16 + cbase;
            sp[(rbl + 0) * 136 + col] = f2bf_hw(acc[rt][nt][0] * d0);
            sp[(rbl + 1) * 136 + col] = f2bf_hw(acc[rt][nt][1] * d1);
            sp[(rbl + 2) * 136 + col] = f2bf_hw(acc[rt][nt][2] * d2);
            sp[(rbl + 3) * 136 + col] = f2bf_hw(acc[rt][nt][3] * d3);
        }
#pragma unroll
        for (int i = 0; i < 4; ++i) {
            int idx = i * 64 + lane;
            int row = idx >> 4, c16 = idx & 15;
            uint4 v = *(const uint4*)(sp + row * 136 + c16 * 8);
            *(uint4*)(Yb + (size_t)(r0g + row) * 256 + c16 * 16) = v;
        }
    }
}

// ---------------- aggregation (padded CSR: no tail loop) ----------------
// T holds T' = (X@W)*dis[src] in bf16 rows of 256B (+ zero row at N_NODES).
// degi holds PADDED counts (multiple of 16). csrb holds BYTE offsets.
template <int POOL>
__global__ __launch_bounds__(256) void aggregate_kernel(
    const ushort* __restrict__ T, const uint* __restrict__ csrb,
    const int* __restrict__ rowptr, const int* __restrict__ degi,
    const float* __restrict__ dis, const float* __restrict__ bias,
    ushort* __restrict__ H, const float* __restrict__ Wfc,
    float* __restrict__ ndot) {
    int wave = threadIdx.x >> 6;
    int node = blockIdx.x * 4 + wave;     // grid exact: N_NODES % 4 == 0
    int lane = threadIdx.x & 63;
    int group = lane >> 4;
    uint sub16 = (uint)(lane & 15) * 16u;

    int start = rowptr[node];
    int iters = degi[node] >> 4;
    const char* Tb = (const char*)T;

    float2 acc[4];
#pragma unroll
    for (int i = 0; i < 4; i++) acc[i] = make_float2(0.f, 0.f);

    int jb = start + group;
    for (int it = 0; it < iters; ++it, jb += 16) {
        uint o0 = csrb[jb];
        uint o1 = csrb[jb + 4];
        uint o2 = csrb[jb + 8];
        uint o3 = csrb[jb + 12];
        uint4 v0 = *(const uint4*)(Tb + (o0 + sub16));
        uint4 v1 = *(const uint4*)(Tb + (o1 + sub16));
        uint4 v2 = *(const uint4*)(Tb + (o2 + sub16));
        uint4 v3 = *(const uint4*)(Tb + (o3 + sub16));
        accp(v0, acc); accp(v1, acc); accp(v2, acc); accp(v3, acc);
    }

#pragma unroll
    for (int i = 0; i < 4; i++) {
        acc[i].x += __shfl_xor(acc[i].x, 16);
        acc[i].y += __shfl_xor(acc[i].y, 16);
        acc[i].x += __shfl_xor(acc[i].x, 32);
        acc[i].y += __shfl_xor(acc[i].y, 32);
    }

    if (group == 0) {
        // self term (weight 1), then scale by dis[node], bias, relu
        uint4 sv = *(const uint4*)(Tb + (((uint)node << 8) + sub16));
        accp(sv, acc);
        float di = dis[node];
        int sub = lane & 15;
        float4 blo = ((const float4*)bias)[sub * 2];
        float4 bhi = ((const float4*)bias)[sub * 2 + 1];
        float bb[8] = {blo.x, blo.y, blo.z, blo.w, bhi.x, bhi.y, bhi.z, bhi.w};
        float r[8];
        float af[8] = {acc[0].x, acc[0].y, acc[1].x, acc[1].y,
                       acc[2].x, acc[2].y, acc[3].x, acc[3].y};
#pragma unroll
        for (int i = 0; i < 8; i++) r[i] = fmaxf(di * af[i] + bb[i], 0.f);
        if (POOL == 0) {
            ((uint4*)H)[(size_t)node * 16 + sub] = pack8(r);
        } else {
            float4 wlo = ((const float4*)Wfc)[sub * 2];
            float4 whi = ((const float4*)Wfc)[sub * 2 + 1];
            float d = r[0] * wlo.x + r[1] * wlo.y + r[2] * wlo.z + r[3] * wlo.w
                    + r[4] * whi.x + r[5] * whi.y + r[6] * whi.z + r[7] * whi.w;
            d += __shfl_xor(d, 1);
            d += __shfl_xor(d, 2);
            d += __shfl_xor(d, 4);
            d += __shfl_xor(d, 8);
            if (sub == 0) ndot[node] = d;   // plain store, no atomic, no barrier
        }
    }
}

// ---------------- pool+fc: one wave per graph over sorted batch ----------------
__global__ __launch_bounds__(64) void pool_fc_kernel(const float* __restrict__ ndot,
                                                     const int* __restrict__ batch,
                                                     const float* __restrict__ bfc,
                                                     float* __restrict__ out) {
    int g = blockIdx.x;
    int lane = threadIdx.x;
    auto lb = [&](int key) {
        int lo = 0, hi = N_NODES;
        while (lo < hi) {
            int mid = (lo + hi) >> 1;
            if (batch[mid] < key) lo = mid + 1; else hi = mid;
        }
        return lo;
    };
    int a = lb(g), b = lb(g + 1);
    float s = 0.f;
    for (int i = a + lane; i < b; i += 64) s += ndot[i];
#pragma unroll
    for (int off = 32; off > 0; off >>= 1) s += __shfl_down(s, off);
    if (lane == 0) out[g] = s / fmaxf((float)(b - a), 1.0f) + bfc[0];
}

// ---------------- launcher ----------------
extern "C" void kernel_launch(void* const* d_in, const int* in_sizes, int n_in,
                              void* d_out, int out_size, void* d_ws, size_t ws_size,
                              hipStream_t stream) {
    const float* x    = (const float*)d_in[0];
    const int*   eidx = (const int*)d_in[1];
    const int*   batch= (const int*)d_in[2];
    const float* W1   = (const float*)d_in[3];
    const float* b1   = (const float*)d_in[4];
    const float* W2   = (const float*)d_in[5];
    const float* b2   = (const float*)d_in[6];
    const float* Wfc  = (const float*)d_in[7];
    const float* bfc  = (const float*)d_in[8];
    float* out = (float*)d_out;

    const int* src = eidx;
    const int* dst = eidx + N_EDGES;

    size_t off = 0;
    char* base = (char*)d_ws;
    auto alloc = [&](size_t bytes) -> void* {
        void* p = base + off;
        off += (bytes + 255) & ~(size_t)255;
        return p;
    };
    int*    bfill  = (int*)alloc(NBUCK * 4);
    ushort* A      = (ushort*)alloc((size_t)(N_NODES + 1) * HID * 2);
    ushort* B      = (ushort*)alloc((size_t)(N_NODES + 1) * HID * 2);
    int*    degi   = (int*)alloc(N_NODES * 4);
    int*    rowptr = (int*)alloc(N_NODES * 4);
    float*  dis    = (float*)alloc(N_NODES * 4);
    float*  ndot   = (float*)alloc(N_NODES * 4);
    uint*   csrb   = (uint*)alloc((size_t)NBUCK * BCAP * 4);
    uint*   bucketed = (uint*)alloc((size_t)NBUCK * BCAP * 4);
    uint4*  WB1    = (uint4*)alloc(2048 * 16);
    uint4*  WB2    = (uint4*)alloc(2048 * 16);

    // init: bfill zeros + dummy zero rows of A and B
    init_kernel<<<1, 256, 0, stream>>>(bfill,
                                       (uint4*)(A + (size_t)N_NODES * HID),
                                       (uint4*)(B + (size_t)N_NODES * HID));

    // bucketed CSR build (fixed-capacity, 2 passes total)
    bucket_scatter_kernel<<<NBLK_A, 256, 0, stream>>>(src, dst, bfill, bucketed);
    bucket_csr_kernel<<<NBUCK, 256, 0, stream>>>(bucketed, bfill, degi, rowptr, dis, csrb);

    // W fragment pre-pack (both layers)
    prep_wfrag2<<<16, 256, 0, stream>>>(W1, W2, WB1, WB2);

    int gemm_grid = (N_NODES + 127) / 128;
    int agg_grid  = N_NODES / 4;   // exact

    // layer 1
    mgemm_kernel<true><<<gemm_grid, 256, 0, stream>>>(x, WB1, dis, A, N_NODES);
    aggregate_kernel<0><<<agg_grid, 256, 0, stream>>>(A, csrb, rowptr, degi, dis, b1, B,
                                                      Wfc, ndot);
    // layer 2
    mgemm_kernel<false><<<gemm_grid, 256, 0, stream>>>(B, WB2, dis, A, N_NODES);
    aggregate_kernel<1><<<agg_grid, 256, 0, stream>>>(A, csrb, rowptr, degi, dis, b2, B,
                                                      Wfc, ndot);

    // pool + fc
    pool_fc_kernel<<<N_GRAPHS, 64, 0, stream>>>(ndot, batch, bfc, out);
}

// Round 12
// 213.161 us; speedup vs baseline: 1.3985x; 1.0674x over previous
//
#include <hip/hip_runtime.h>
#include <hip/hip_bf16.h>

#define N_NODES 100000
#define N_EDGES 1600000
#define HID 128
#define N_GRAPHS 256

#define BSHIFT 9
#define BSIZE 512
#define NBUCK ((N_NODES + BSIZE - 1) / BSIZE)   // 196
#define BCAP 12288
#define EPB 8192
#define NBLK_A ((N_EDGES + EPB - 1) / EPB)      // 196
#define NCLS 16
#define ZOFF ((uint)N_NODES << 8)                // byte offset of the zero row

typedef unsigned int uint;
typedef unsigned short ushort;
typedef short short8 __attribute__((ext_vector_type(8)));
typedef float f32x4 __attribute__((ext_vector_type(4)));

__device__ __forceinline__ ushort f2bf_hw(float f) {
    union { __hip_bfloat16 b; ushort u; } cv;
    cv.b = __float2bfloat16(f);
    return cv.u;
}
__device__ __forceinline__ uint4 pack8(const float* r) {
    uint4 o;
    o.x = (uint)f2bf_hw(r[0]) | ((uint)f2bf_hw(r[1]) << 16);
    o.y = (uint)f2bf_hw(r[2]) | ((uint)f2bf_hw(r[3]) << 16);
    o.z = (uint)f2bf_hw(r[4]) | ((uint)f2bf_hw(r[5]) << 16);
    o.w = (uint)f2bf_hw(r[6]) | ((uint)f2bf_hw(r[7]) << 16);
    return o;
}
// accumulate 8 bf16 (packed uint4) into 4 float2 (paired for v_pk_add_f32)
__device__ __forceinline__ void accp(uint4 v, float2* a) {
    a[0].x += __uint_as_float(v.x << 16);
    a[0].y += __uint_as_float(v.x & 0xFFFF0000u);
    a[1].x += __uint_as_float(v.y << 16);
    a[1].y += __uint_as_float(v.y & 0xFFFF0000u);
    a[2].x += __uint_as_float(v.z << 16);
    a[2].y += __uint_as_float(v.z & 0xFFFF0000u);
    a[3].x += __uint_as_float(v.w << 16);
    a[3].y += __uint_as_float(v.w & 0xFFFF0000u);
}

union Frag16 {
    uint4 u;
    short8 s;
    ushort h[8];
};

// ---------------- setup: zero counters + zero rows, and pack W frags ----------------
__global__ void setup_kernel(int* __restrict__ bfill, int* __restrict__ clshist,
                             int* __restrict__ clsfill,
                             uint4* __restrict__ Azr, uint4* __restrict__ Bzr,
                             const float* __restrict__ W1, const float* __restrict__ W2,
                             uint4* __restrict__ WB1, uint4* __restrict__ WB2) {
    if (blockIdx.x == 0) {
        int t = threadIdx.x;
        if (t < NBUCK) bfill[t] = 0;
        if (t < NCLS) { clshist[t] = 0; clsfill[t] = 0; }
        if (t < 16) Azr[t] = (uint4){0, 0, 0, 0};
        else if (t < 32) Bzr[t - 16] = (uint4){0, 0, 0, 0};
        return;
    }
    int t = (blockIdx.x - 1) * 256 + threadIdx.x;   // 0..4095
    const float* W = (t < 2048) ? W1 : W2;
    uint4* WB = (t < 2048) ? WB1 : WB2;
    int tt = t & 2047;
    int lane = tt & 63;
    int nt = (tt >> 6) & 7;
    int kt = tt >> 9;
    int kbase = kt * 32 + (lane >> 4) * 8;
    int col = nt * 16 + (lane & 15);
    float r[8];
#pragma unroll
    for (int j = 0; j < 8; j++) r[j] = W[(size_t)(kbase + j) * 128 + col];
    WB[tt] = pack8(r);
}

// ---------------- bucketed CSR build ----------------
__global__ __launch_bounds__(256) void bucket_scatter_kernel(const int* __restrict__ src,
                                                             const int* __restrict__ dst,
                                                             int* __restrict__ bfill,
                                                             uint* __restrict__ bucketed) {
    __shared__ int h[NBUCK];
    __shared__ int rb[NBUCK];
    for (int t = threadIdx.x; t < NBUCK; t += 256) h[t] = 0;
    __syncthreads();
    int base = blockIdx.x * EPB;
#pragma unroll 4
    for (int it = 0; it < EPB / 256; ++it) {
        int e = base + it * 256 + threadIdx.x;
        if (e < N_EDGES) atomicAdd(&h[dst[e] >> BSHIFT], 1);
    }
    __syncthreads();
    for (int t = threadIdx.x; t < NBUCK; t += 256) {
        rb[t] = (h[t] ? atomicAdd(&bfill[t], h[t]) : 0) + t * BCAP;
        h[t] = 0;
    }
    __syncthreads();
#pragma unroll 4
    for (int it = 0; it < EPB / 256; ++it) {
        int e = base + it * 256 + threadIdx.x;
        if (e < N_EDGES) {
            int d = dst[e];
            int b = d >> BSHIFT;
            int pos = rb[b] + atomicAdd(&h[b], 1);
            bucketed[pos] = (uint)src[e] | ((uint)(d & (BSIZE - 1)) << 17);
        }
    }
}

// one block per bucket: count/scan/scatter. Segments padded to multiple of 4 (ZOFF fill);
// degi holds PADDED count; also builds the degree-class histogram.
__global__ __launch_bounds__(256) void bucket_csr_kernel(const uint* __restrict__ bucketed,
                                                         const int* __restrict__ bfill,
                                                         int* __restrict__ degi,
                                                         int* __restrict__ rowptr,
                                                         float* __restrict__ dis,
                                                         uint* __restrict__ csrb,
                                                         int* __restrict__ clshist) {
    int b = blockIdx.x;
    int beg = b * BCAP;
    int ne = bfill[b];
    __shared__ int cnt[BSIZE];
    __shared__ int fl[BSIZE];
    __shared__ int ex[BSIZE];
    __shared__ int ps[256];
    __shared__ int ch[NCLS];
    int t = threadIdx.x;
    cnt[t] = 0; cnt[t + 256] = 0;
    fl[t] = 0;  fl[t + 256] = 0;
    if (t < NCLS) ch[t] = 0;
    __syncthreads();
    for (int i = t; i < ne; i += 256) atomicAdd(&cnt[bucketed[beg + i] >> 17], 1);
    __syncthreads();
    int v0 = cnt[2 * t], v1 = cnt[2 * t + 1];
    int p0 = (v0 + 3) & ~3;
    int p1 = (v1 + 3) & ~3;
    int s = p0 + p1;
    ps[t] = s;
    __syncthreads();
    for (int off = 1; off < 256; off <<= 1) {
        int a = (t >= off) ? ps[t - off] : 0;
        __syncthreads();
        ps[t] += a;
        __syncthreads();
    }
    int e0 = ps[t] - s;
    ex[2 * t] = e0;
    ex[2 * t + 1] = e0 + p0;
    int g = b * BSIZE + 2 * t;
    if (g < N_NODES) {
        degi[g] = p0; rowptr[g] = beg + e0;
        dis[g] = rsqrtf(1.0f + (float)v0);
        atomicAdd(&ch[min(p0 >> 2, NCLS - 1)], 1);
    }
    if (g + 1 < N_NODES) {
        degi[g + 1] = p1; rowptr[g + 1] = beg + e0 + p0;
        dis[g + 1] = rsqrtf(1.0f + (float)v1);
        atomicAdd(&ch[min(p1 >> 2, NCLS - 1)], 1);
    }
    __syncthreads();
    if (t < NCLS && ch[t]) atomicAdd(&clshist[t], ch[t]);
    for (int i = t; i < ne; i += 256) {
        uint u = bucketed[beg + i];
        int dl = u >> 17;
        int p = ex[dl] + atomicAdd(&fl[dl], 1);
        csrb[beg + p] = (u & 0x1FFFFu) << 8;   // byte offset: src * 256
    }
    __syncthreads();
    for (int p = v0; p < p0; ++p) csrb[beg + ex[2 * t] + p] = ZOFF;
    for (int p = v1; p < p1; ++p) csrb[beg + ex[2 * t + 1] + p] = ZOFF;
}

// ---------------- class bases (16 values, serial) ----------------
__global__ void clsbase_kernel(const int* __restrict__ clshist, int* __restrict__ clsbase) {
    if (threadIdx.x == 0) {
        int run = 0;
        for (int c = 0; c < NCLS; ++c) { clsbase[c] = run; run += clshist[c]; }
    }
}

// ---------------- degree-class permutation (hierarchical, low-contention) ----------------
__global__ __launch_bounds__(256) void perm_kernel(const int* __restrict__ degi,
                                                   const int* __restrict__ clsbase,
                                                   int* __restrict__ clsfill,
                                                   int* __restrict__ perm) {
    __shared__ int h[NCLS];
    __shared__ int rb[NCLS];
    int t = threadIdx.x;
    if (t < NCLS) h[t] = 0;
    __syncthreads();
    int n = blockIdx.x * 256 + t;
    int cls = 0, myloc = 0;
    if (n < N_NODES) {
        cls = min(degi[n] >> 2, NCLS - 1);
        myloc = atomicAdd(&h[cls], 1);
    }
    __syncthreads();
    if (t < NCLS) rb[t] = h[t] ? (clsbase[t] + atomicAdd(&clsfill[t], h[t])) : 0;
    __syncthreads();
    if (n < N_NODES) perm[rb[cls] + myloc] = n;
}

// ---------------- xprep: X' = bf16(dis[n] * x[n]) ----------------
__global__ __launch_bounds__(256) void xprep_kernel(const float* __restrict__ x,
                                                    const float* __restrict__ dis,
                                                    uint4* __restrict__ Xp) {
    int t = blockIdx.x * 256 + threadIdx.x;      // 1.6M = N_NODES*16
    if (t >= N_NODES * 16) return;
    int n = t >> 4, c16 = t & 15;
    const float* xr = x + (size_t)n * 128 + c16 * 8;
    float d = dis[n];
    float4 lo = *(const float4*)xr;
    float4 hi = *(const float4*)(xr + 4);
    float r[8] = {d * lo.x, d * lo.y, d * lo.z, d * lo.w,
                  d * hi.x, d * hi.y, d * hi.z, d * hi.w};
    Xp[t] = pack8(r);
}

// ---------------- fused aggregate + GEMM (+ optional pool dot) ----------------
// Block = 16 nodes (class-uniform via perm). Group (16 lanes) owns one node's gather.
// u = dis[n]*(sum_nbr T[s] + T[n]) -> A-tile (bf16, LDS) -> M=16 MFMA @ W -> epilogue.
// POOL=0: H[n] = bf16(dis[n]*relu(u@W + b));  POOL=1: ndot[n] = relu(u@W + b) . Wfc
template <int POOL>
__global__ __launch_bounds__(256, 8) void fused_agg_kernel(
    const ushort* __restrict__ T, const uint* __restrict__ csrb,
    const int* __restrict__ rowptr, const int* __restrict__ degi,
    const float* __restrict__ dis, const float* __restrict__ bias,
    const int* __restrict__ perm, const uint4* __restrict__ WB,
    ushort* __restrict__ H, const float* __restrict__ Wfc,
    float* __restrict__ ndot) {
    __shared__ ushort At[16][136];      // 272B row stride (bank-spread)
    __shared__ float disrow[16];
    __shared__ int nid[16];
    __shared__ float pdot[16][4];

    int wave = threadIdx.x >> 6;
    int lane = threadIdx.x & 63;
    int group = lane >> 4;
    int sub = lane & 15;
    uint sub16 = (uint)sub * 16u;
    int r = wave * 4 + group;                       // tile row 0..15
    int node = perm[blockIdx.x * 16 + r];           // grid exact: N_NODES%16==0
    int start = rowptr[node];
    int iters = degi[node] >> 2;
    const char* Tb = (const char*)T;

    float2 acc[4];
#pragma unroll
    for (int i = 0; i < 4; i++) acc[i] = make_float2(0.f, 0.f);

    int jb = start;
    for (int it = 0; it < iters; ++it, jb += 4) {
        uint o0 = csrb[jb];
        uint o1 = csrb[jb + 1];
        uint o2 = csrb[jb + 2];
        uint o3 = csrb[jb + 3];
        uint4 v0 = *(const uint4*)(Tb + (o0 + sub16));
        uint4 v1 = *(const uint4*)(Tb + (o1 + sub16));
        uint4 v2 = *(const uint4*)(Tb + (o2 + sub16));
        uint4 v3 = *(const uint4*)(Tb + (o3 + sub16));
        accp(v0, acc); accp(v1, acc); accp(v2, acc); accp(v3, acc);
    }
    // self term, then scale by dis[node] -> u-row (bf16) into A tile
    {
        uint4 sv = *(const uint4*)(Tb + (((uint)node << 8) + sub16));
        accp(sv, acc);
        float di = dis[node];
        float rr[8] = {di * acc[0].x, di * acc[0].y, di * acc[1].x, di * acc[1].y,
                       di * acc[2].x, di * acc[2].y, di * acc[3].x, di * acc[3].y};
        *(uint4*)&At[r][sub * 8] = pack8(rr);
        if (sub == 0) { disrow[r] = di; nid[r] = node; }
    }
    __syncthreads();

    // MFMA: wave handles nt = wave*2, wave*2+1 over the 16x128 tile
    Frag16 a[4];
    int arow = lane & 15;
    int achunk = lane >> 4;
#pragma unroll
    for (int kt = 0; kt < 4; ++kt)
        a[kt].u = *(const uint4*)&At[arow][kt * 32 + achunk * 8];

    f32x4 c0 = (f32x4){0.f, 0.f, 0.f, 0.f};
    f32x4 c1 = (f32x4){0.f, 0.f, 0.f, 0.f};
    int nt0 = wave * 2, nt1 = wave * 2 + 1;
#pragma unroll
    for (int kt = 0; kt < 4; ++kt) {
        Frag16 b0, b1;
        b0.u = WB[(kt * 8 + nt0) * 64 + lane];
        b1.u = WB[(kt * 8 + nt1) * 64 + lane];
        c0 = __builtin_amdgcn_mfma_f32_16x16x32_bf16(a[kt].s, b0.s, c0, 0, 0, 0);
        c1 = __builtin_amdgcn_mfma_f32_16x16x32_bf16(a[kt].s, b1.s, c1, 0, 0, 0);
    }

    // C layout: col = lane&15, row = (lane>>4)*4 + reg
    int col0 = nt0 * 16 + sub, col1 = nt1 * 16 + sub;
    float b0s = bias[col0], b1s = bias[col1];
    int rq = (lane >> 4) * 4;

    if (POOL == 0) {
        __syncthreads();   // all A-reads done; reuse At as output stage
#pragma unroll
        for (int reg = 0; reg < 4; ++reg) {
            float sc = disrow[rq + reg];
            At[rq + reg][col0] = f2bf_hw(fmaxf(c0[reg] + b0s, 0.f) * sc);
            At[rq + reg][col1] = f2bf_hw(fmaxf(c1[reg] + b1s, 0.f) * sc);
        }
        __syncthreads();
        int row = threadIdx.x >> 4, c16 = threadIdx.x & 15;
        uint4 v = *(const uint4*)&At[row][c16 * 8];
        *(uint4*)((char*)H + (((size_t)(uint)nid[row]) << 8) + c16 * 16) = v;
    } else {
        float wf0 = Wfc[col0], wf1 = Wfc[col1];
        float p[4];
#pragma unroll
        for (int reg = 0; reg < 4; ++reg)
            p[reg] = fmaxf(c0[reg] + b0s, 0.f) * wf0 + fmaxf(c1[reg] + b1s, 0.f) * wf1;
#pragma unroll
        for (int reg = 0; reg < 4; ++reg) {
            p[reg] += __shfl_xor(p[reg], 1);
            p[reg] += __shfl_xor(p[reg], 2);
            p[reg] += __shfl_xor(p[reg], 4);
            p[reg] += __shfl_xor(p[reg], 8);
        }
        if (sub == 0) {
#pragma unroll
            for (int reg = 0; reg < 4; ++reg) pdot[rq + reg][wave] = p[reg];
        }
        __syncthreads();
        if (threadIdx.x < 16) {
            int row = threadIdx.x;
            ndot[nid[row]] = pdot[row][0] + pdot[row][1] + pdot[row][2] + pdot[row][3];
        }
    }
}

// ---------------- pool+fc: one wave per graph over sorted batch ----------------
__global__ __launch_bounds__(64) void pool_fc_kernel(const float* __restrict__ ndot,
                                                     const int* __restrict__ batch,
                                                     const float* __restrict__ bfc,
                                                     float* __restrict__ out) {
    int g = blockIdx.x;
    int lane = threadIdx.x;
    auto lb = [&](int key) {
        int lo = 0, hi = N_NODES;
        while (lo < hi) {
            int mid = (lo + hi) >> 1;
            if (batch[mid] < key) lo = mid + 1; else hi = mid;
        }
        return lo;
    };
    int a = lb(g), b = lb(g + 1);
    float s = 0.f;
    for (int i = a + lane; i < b; i += 64) s += ndot[i];
#pragma unroll
    for (int off = 32; off > 0; off >>= 1) s += __shfl_down(s, off);
    if (lane == 0) out[g] = s / fmaxf((float)(b - a), 1.0f) + bfc[0];
}

// ---------------- launcher ----------------
extern "C" void kernel_launch(void* const* d_in, const int* in_sizes, int n_in,
                              void* d_out, int out_size, void* d_ws, size_t ws_size,
                              hipStream_t stream) {
    const float* x    = (const float*)d_in[0];
    const int*   eidx = (const int*)d_in[1];
    const int*   batch= (const int*)d_in[2];
    const float* W1   = (const float*)d_in[3];
    const float* b1   = (const float*)d_in[4];
    const float* W2   = (const float*)d_in[5];
    const float* b2   = (const float*)d_in[6];
    const float* Wfc  = (const float*)d_in[7];
    const float* bfc  = (const float*)d_in[8];
    float* out = (float*)d_out;

    const int* src = eidx;
    const int* dst = eidx + N_EDGES;

    size_t off = 0;
    char* base = (char*)d_ws;
    auto alloc = [&](size_t bytes) -> void* {
        void* p = base + off;
        off += (bytes + 255) & ~(size_t)255;
        return p;
    };
    int*    bfill   = (int*)alloc(NBUCK * 4);
    int*    clshist = (int*)alloc(NCLS * 4);
    int*    clsfill = (int*)alloc(NCLS * 4);
    int*    clsbase = (int*)alloc(NCLS * 4);
    ushort* A       = (ushort*)alloc((size_t)(N_NODES + 1) * HID * 2);
    ushort* B       = (ushort*)alloc((size_t)(N_NODES + 1) * HID * 2);
    int*    degi    = (int*)alloc(N_NODES * 4);
    int*    rowptr  = (int*)alloc(N_NODES * 4);
    float*  dis     = (float*)alloc(N_NODES * 4);
    float*  ndot    = (float*)alloc(N_NODES * 4);
    int*    perm    = (int*)alloc(N_NODES * 4);
    uint*   csrb    = (uint*)alloc((size_t)NBUCK * BCAP * 4);
    uint*   bucketed= (uint*)alloc((size_t)NBUCK * BCAP * 4);
    uint4*  WB1     = (uint4*)alloc(2048 * 16);
    uint4*  WB2     = (uint4*)alloc(2048 * 16);

    // setup: zero counters + zero rows + W frag pack
    setup_kernel<<<17, 256, 0, stream>>>(bfill, clshist, clsfill,
                                         (uint4*)(A + (size_t)N_NODES * HID),
                                         (uint4*)(B + (size_t)N_NODES * HID),
                                         W1, W2, WB1, WB2);

    // bucketed CSR build (pad-4 + class histogram)
    bucket_scatter_kernel<<<NBLK_A, 256, 0, stream>>>(src, dst, bfill, bucketed);
    bucket_csr_kernel<<<NBUCK, 256, 0, stream>>>(bucketed, bfill, degi, rowptr, dis,
                                                 csrb, clshist);
    clsbase_kernel<<<1, 64, 0, stream>>>(clshist, clsbase);
    perm_kernel<<<(N_NODES + 255) / 256, 256, 0, stream>>>(degi, clsbase, clsfill, perm);

    // X' = bf16(dis * x)
    xprep_kernel<<<(N_NODES * 16 + 255) / 256, 256, 0, stream>>>(x, dis, (uint4*)A);

    int fgrid = N_NODES / 16;   // 6250 exact

    // layer 1: gather X' -> @W1 -> relu -> *dis -> B (h1')
    fused_agg_kernel<0><<<fgrid, 256, 0, stream>>>(A, csrb, rowptr, degi, dis, b1,
                                                   perm, WB1, B, Wfc, ndot);
    // layer 2: gather h1' -> @W2 -> relu -> dot Wfc -> ndot
    fused_agg_kernel<1><<<fgrid, 256, 0, stream>>>(B, csrb, rowptr, degi, dis, b2,
                                                   perm, WB2, B, Wfc, ndot);

    // pool + fc
    pool_fc_kernel<<<N_GRAPHS, 64, 0, stream>>>(ndot, batch, bfc, out);
}